// Round 11
// baseline (131453.394 us; speedup 1.0000x reference)
//
#include <hip/hip_runtime.h>

#define NSAMP 16384
#define NSTEP 32

typedef __attribute__((ext_vector_type(8))) short bf16x8;
typedef __attribute__((ext_vector_type(4))) short short4v;
typedef __attribute__((ext_vector_type(4))) float f32x4;
typedef __attribute__((ext_vector_type(2))) unsigned int uint2v;
typedef __attribute__((ext_vector_type(4))) unsigned int uint4v;

__device__ __forceinline__ unsigned short f2bf(float f) {
    unsigned int u = __float_as_uint(f);
    u += 0x7FFFu + ((u >> 16) & 1u);
    return (unsigned short)(u >> 16);
}
__device__ __forceinline__ float bf2fs(short h) {
    return __uint_as_float(((unsigned int)(unsigned short)h) << 16);
}
__device__ __forceinline__ unsigned int cvtpk(float a, float b) {
    unsigned int r;
    asm("v_cvt_pk_bf16_f32 %0, %1, %2" : "=v"(r) : "v"(a), "v"(b));
    return r;
}
__device__ __forceinline__ float ftanh(float x) {
    float e = __expf(2.0f * x);
    return 1.0f - __fdividef(2.0f, e + 1.0f);
}

// ---------------- prep: pack weights to bf16 in d_ws (unchanged) ----------------
__global__ void prep_kernel(const float* __restrict__ W1, const float* __restrict__ W2,
                            const float* __restrict__ W3, const float* __restrict__ W4,
                            unsigned short* __restrict__ ws) {
    int j = blockIdx.x * blockDim.x + threadIdx.x;   // 0..65535
    if (j < 65536) {
        int e = j & 7, l = (j >> 3) & 63, s = (j >> 9) & 1, ks = (j >> 10) & 7, w = j >> 13;
        int m = (w << 5) + (s << 4) + (l & 15);
        int k = (ks << 5) + ((l >> 4) << 3) + e;
        ws[j]         = f2bf(W2[m * 256 + k]);
        ws[65536 + j] = f2bf(W3[m * 256 + k]);
    }
    if (j < 16384) {
        int i = j >> 8, k = j & 255;
        ws[131072 + j] = f2bf(W1[k * 64 + i]);   // W1T[i][k]
        ws[147456 + j] = f2bf(W4[j]);            // W4 [i][k]
        int e = j & 7, l = (j >> 3) & 63, ms = (j >> 9) & 1, ks = (j >> 10) & 1, w = j >> 11;
        int m = (w << 5) + (ms << 4) + (l & 15);
        int i2 = (ks << 5) + ((l >> 4) << 3) + e;
        ws[163840 + j] = f2bf(W1[m * 64 + i2]);  // W1 A-frags (K=64)
    }
}

// ---------------- main kernel ----------------
// Block = 2 samples, 8 waves. Waves 0-3 own sample 0, waves 4-7 sample 1;
// each wave computes 64 output rows ((w&3)*64..+64) of its sample's GEMMs, so
// each tangent panel is read by only 4 waves (was 8) and the h-tile read is a
// wave-uniform broadcast. One alternating 128-VGPR weight bank (W2 during G1,
// W3 during G2, reloaded from L2; WAR on the bank regs orders the loads).
// 5 barriers/eval: P1(zMFMA+h1/d1+BUILD both) | P2(G1+epi2) | P3(A2 writes) |
// P4(G2+epi3+div) | P5(dz+RK+ZBT).

#define MFMA(A, B, C) __builtin_amdgcn_mfma_f32_16x16x32_bf16(A, B, C, 0, 0, 0)

#define ZERO_ACC()                                                           \
    _Pragma("unroll") for (int ms = 0; ms < 4; ++ms)                         \
    _Pragma("unroll") for (int t = 0; t < 5; ++t)                            \
        acc[ms][t] = (f32x4){0.f, 0.f, 0.f, 0.f};

// G: 5 B-tiles (4 tangent of own sample + broadcast h-row), 4 m-tiles.
#define GEMM_ALL(HROW)                                                       \
    __builtin_amdgcn_s_setprio(1);                                           \
    _Pragma("unroll") for (int ks = 0; ks < 8; ++ks) {                       \
        const int kr = (ks << 5) + kband;                                    \
        const bf16x8 bh = *(const bf16x8*)&XT[(HROW) * 264 + kr];            \
        _Pragma("unroll") for (int ms = 0; ms < 4; ++ms)                     \
            acc[ms][4] = MFMA(wbank[ks][ms], bh, acc[ms][4]);                \
        _Pragma("unroll") for (int t = 0; t < 4; ++t) {                      \
            const bf16x8 bt = *(const bf16x8*)&XT[(sbase + (t << 4) + lm) * 264 + kr]; \
            _Pragma("unroll") for (int ms = 0; ms < 4; ++ms)                 \
                acc[ms][t] = MFMA(wbank[ks][ms], bt, acc[ms][t]);            \
        }                                                                    \
    }                                                                        \
    __builtin_amdgcn_s_setprio(0);

// load one weight matrix's 32 fragments (128 VGPR) for this wave's 4 m-tiles
#define LOAD_BANK(SRC)                                                       \
    _Pragma("unroll") for (int ks = 0; ks < 8; ++ks)                         \
    _Pragma("unroll") for (int ms = 0; ms < 4; ++ms) {                       \
        const int t_ = ((w & 3) << 2) + ms;                                  \
        wbank[ks][ms] = SRC[((((t_ >> 1) << 3) + ks) * 2 + (t_ & 1)) * 64 + l]; \
    }

// column-sliced tangent build (bf16 d1), wave w -> k-cols [32w,32w+32)
#define BUILD(S)                                                             \
    { _Pragma("unroll") for (int c = 0; c < 4; ++c) {                        \
        const int kk = kcol0 + (c << 3);                                     \
        const bf16x8 wv = *(const bf16x8*)&W1T[l * 264 + kk];                \
        const bf16x8 dq = *(const bf16x8*)&dvec1[(S) * 256 + kk];            \
        uint4v o;                                                            \
        o[0] = cvtpk(bf2fs(wv[0]) * bf2fs(dq[0]), bf2fs(wv[1]) * bf2fs(dq[1])); \
        o[1] = cvtpk(bf2fs(wv[2]) * bf2fs(dq[2]), bf2fs(wv[3]) * bf2fs(dq[3])); \
        o[2] = cvtpk(bf2fs(wv[4]) * bf2fs(dq[4]), bf2fs(wv[5]) * bf2fs(dq[5])); \
        o[3] = cvtpk(bf2fs(wv[6]) * bf2fs(dq[6]), bf2fs(wv[7]) * bf2fs(dq[7])); \
        *(uint4v*)&XT[((S) * 64 + l) * 264 + kk] = o;                        \
    } }

__launch_bounds__(512, 2)
__global__ void cnf_kernel(const float* __restrict__ zin,
                           const float* __restrict__ b1g, const float* __restrict__ b2g,
                           const float* __restrict__ b3g, const float* __restrict__ b4g,
                           const unsigned short* __restrict__ ws,
                           float* __restrict__ out)
{
    __shared__ __align__(16) unsigned short XT[132 * 264];   // 69.7 KB
    __shared__ __align__(16) unsigned short W1T[64 * 264];   // 33.8 KB
    __shared__ __align__(16) unsigned short W4L[64 * 264];   // 33.8 KB
    __shared__ __align__(16) unsigned short ZBT[16 * 72];    // 2.3 KB
    __shared__ __align__(16) unsigned short dvec1[512];      // bf16 d1 (2 samples)
    __shared__ __align__(16) unsigned short hvec[512];       // bf16 h3
    __shared__ __align__(16) float b1l[256], b2l[256], b3l[256];
    __shared__ float wredp[8];
    __shared__ float misc[4];   // [0..1]=ka_logp per s, [2..3]=logp per s

    const int tid = threadIdx.x;
    const int w = tid >> 6;
    const int l = tid & 63;
    const int lm = l & 15;
    const int bid = blockIdx.x;
    const int r0 = (w << 5) + ((l >> 4) << 2);          // M=32 mapping (P1)
    const int r064 = ((w & 3) << 6) + ((l >> 4) << 2);  // M=64 mapping (GEMM)
    const int kband = (l >> 4) << 3;
    const int kcol0 = w << 5;
    const int s = w >> 2;              // this wave's sample
    const int sbase = s << 6;          // tangent panel row base
    const int iown = ((w & 3) << 4) + lm;
    const float DT = -1.0f / 32.0f;

    const bf16x8* w2g = (const bf16x8*)ws;
    const bf16x8* w3g = w2g + 8192;
    const bf16x8* w1g = (const bf16x8*)(ws + 163840);

    const float b4r = b4g[iown];
    float zreg = zin[(bid * 2 + s) * 64 + iown];
    float kreg = 0.f;

    bf16x8 wbank[8][4];
    LOAD_BANK(w2g)

    // ---- LDS init ----
    for (int c = tid; c < 2048; c += 512) {
        int i = c >> 5, k0 = (c & 31) << 3;
        *(bf16x8*)&W1T[i * 264 + k0] = *(const bf16x8*)&ws[131072 + i * 256 + k0];
        *(bf16x8*)&W4L[i * 264 + k0] = *(const bf16x8*)&ws[147456 + i * 256 + k0];
    }
    for (int c = 144 + tid; c < 1152; c += 512) ZBT[c] = 0;   // zero rows 2-15
    if (tid < 256) { b1l[tid] = b1g[tid]; b2l[tid] = b2g[tid]; b3l[tid] = b3g[tid]; }
    if (tid < 128) {
        const int ss = tid >> 6, i = tid & 63;
        ZBT[ss * 72 + i] = f2bf(zin[(bid * 2 + ss) * 64 + i]);
    }
    if (tid < 2) { misc[tid] = 0.f; misc[2 + tid] = 0.f; }
    __syncthreads();

    for (int it = 0; it < NSTEP * 4; ++it) {
        const int e = it & 3;
        f32x4 acc[4][5];
        float d2r[4][4];

        // ======== P1: deferred logp + z-MFMA (h1/d1 both samples) + builds ===
        if (it > 0 && tid < 2) {
            const int ep = (it - 1) & 3;
            float div = wredp[tid * 4] + wredp[tid * 4 + 1] +
                        wredp[tid * 4 + 2] + wredp[tid * 4 + 3];
            const float wgt = (ep == 0 || ep == 3) ? 1.f : 2.f;
            float kl = (ep == 0) ? -div : misc[tid] - wgt * div;
            misc[tid] = kl;
            if (ep == 3) misc[2 + tid] += (DT / 6.0f) * kl;
        }
        {
            f32x4 az[2];
            az[0] = (f32x4){0.f, 0.f, 0.f, 0.f};
            az[1] = (f32x4){0.f, 0.f, 0.f, 0.f};
#pragma unroll
            for (int ks = 0; ks < 2; ++ks) {
                const bf16x8 zf = *(const bf16x8*)&ZBT[lm * 72 + (ks << 5) + kband];
                az[0] = MFMA(w1g[(((w << 1) + ks) * 2 + 0) * 64 + l], zf, az[0]);
                az[1] = MFMA(w1g[(((w << 1) + ks) * 2 + 1) * 64 + l], zf, az[1]);
            }
#pragma unroll
            for (int ms = 0; ms < 2; ++ms) {
                const int rb = r0 + (ms << 4);
                float hh[4], dd[4];
#pragma unroll
                for (int rg = 0; rg < 4; ++rg) {
                    float h = ftanh(az[ms][rg] + b1l[rb + rg]);
                    hh[rg] = h; dd[rg] = 1.f - h * h;
                }
                if (lm < 2) {
                    uint2v dp; dp[0] = cvtpk(dd[0], dd[1]); dp[1] = cvtpk(dd[2], dd[3]);
                    *(uint2v*)&dvec1[lm * 256 + rb] = dp;
                    uint2v hp; hp[0] = cvtpk(hh[0], hh[1]); hp[1] = cvtpk(hh[2], hh[3]);
                    *(uint2v*)&XT[(128 + lm) * 264 + rb] = hp;
                }
            }
        }
        BUILD(0)
        BUILD(1)
        __syncthreads();

        // ======== P2: GEMM1 (own sample, 64 rows) + epi2 + W3 bank load ======
        ZERO_ACC()
        GEMM_ALL(128 + s)
#pragma unroll
        for (int ms = 0; ms < 4; ++ms) {
            const int rb = r064 + (ms << 4);
            float hh[4];
#pragma unroll
            for (int rg = 0; rg < 4; ++rg) {
                float h = ftanh(acc[ms][4][rg] + b2l[rb + rg]);
                hh[rg] = h; d2r[ms][rg] = 1.f - h * h;
            }
            if (lm == 0) {
                uint2v hp; hp[0] = cvtpk(hh[0], hh[1]); hp[1] = cvtpk(hh[2], hh[3]);
                *(uint2v*)&XT[(130 + s) * 264 + rb] = hp;
            }
        }
        LOAD_BANK(w3g)   // WAR on wbank: issues after G1's last MFMA
        __syncthreads();

        // ======== P3: A2 scale-writes (overwrite own sample's tangent panel) =
#pragma unroll
        for (int ms = 0; ms < 4; ++ms) {
            const int rb = r064 + (ms << 4);
#pragma unroll
            for (int ns = 0; ns < 4; ++ns) {
                uint2v o;
                o[0] = cvtpk(acc[ms][ns][0] * d2r[ms][0], acc[ms][ns][1] * d2r[ms][1]);
                o[1] = cvtpk(acc[ms][ns][2] * d2r[ms][2], acc[ms][ns][3] * d2r[ms][3]);
                *(uint2v*)&XT[(sbase + (ns << 4) + lm) * 264 + rb] = o;
            }
        }
        __syncthreads();

        // ======== P4: GEMM2 + epi3 (h3, div partials) + W2 bank reload =======
        ZERO_ACC()
        GEMM_ALL(130 + s)
        {
            float p = 0.f;
#pragma unroll
            for (int ms = 0; ms < 4; ++ms) {
                const int rb = r064 + (ms << 4);
                float hh[4], dd[4];
#pragma unroll
                for (int rg = 0; rg < 4; ++rg) {
                    float h = ftanh(acc[ms][4][rg] + b3l[rb + rg]);
                    hh[rg] = h; dd[rg] = 1.f - h * h;
                }
                if (lm == 0) {
                    uint2v hp; hp[0] = cvtpk(hh[0], hh[1]); hp[1] = cvtpk(hh[2], hh[3]);
                    *(uint2v*)&hvec[s * 256 + rb] = hp;
                }
#pragma unroll
                for (int ns = 0; ns < 4; ++ns) {
                    const short4v wv = *(const short4v*)&W4L[((ns << 4) + lm) * 264 + rb];
                    p += acc[ms][ns][0] * dd[0] * bf2fs(wv[0]);
                    p += acc[ms][ns][1] * dd[1] * bf2fs(wv[1]);
                    p += acc[ms][ns][2] * dd[2] * bf2fs(wv[2]);
                    p += acc[ms][ns][3] * dd[3] * bf2fs(wv[3]);
                }
            }
#pragma unroll
            for (int o = 32; o; o >>= 1) p += __shfl_xor(p, o, 64);
            if (l == 0) wredp[w] = p;
        }
        LOAD_BANK(w2g)   // for next eval's G1
        __syncthreads();

        // ======== P5: dz matvec + RK + ZBT ========
        {
            const int ch = l >> 4;
            float a = 0.f;
#pragma unroll
            for (int c = 0; c < 8; ++c) {
                const bf16x8 wv = *(const bf16x8*)&W4L[iown * 264 + (ch << 6) + (c << 3)];
                const bf16x8 hb = *(const bf16x8*)&hvec[s * 256 + (ch << 6) + (c << 3)];
                a += bf2fs(wv[0]) * bf2fs(hb[0]) + bf2fs(wv[1]) * bf2fs(hb[1]);
                a += bf2fs(wv[2]) * bf2fs(hb[2]) + bf2fs(wv[3]) * bf2fs(hb[3]);
                a += bf2fs(wv[4]) * bf2fs(hb[4]) + bf2fs(wv[5]) * bf2fs(hb[5]);
                a += bf2fs(wv[6]) * bf2fs(hb[6]) + bf2fs(wv[7]) * bf2fs(hb[7]);
            }
            a += __shfl_xor(a, 16, 64);
            a += __shfl_xor(a, 32, 64);
            const float dz = a + b4r;

            const float wgt = (e == 0 || e == 3) ? 1.f : 2.f;
            const float kv = (e == 0) ? dz : kreg + wgt * dz;
            kreg = kv;
            float znew;
            if (e < 3) {
                znew = zreg + ((e == 2) ? 1.0f : 0.5f) * DT * dz;
            } else {
                znew = zreg + (DT / 6.0f) * kv;
                zreg = znew;
            }
            if (l < 16) ZBT[s * 72 + iown] = f2bf(znew);
        }
        __syncthreads();
    }

    // final outputs
    if (l < 16) out[(bid * 2 + s) * 64 + iown] = zreg;
    if (tid < 2) {
        float div = wredp[tid * 4] + wredp[tid * 4 + 1] +
                    wredp[tid * 4 + 2] + wredp[tid * 4 + 3];
        float kl = misc[tid] - div;
        out[NSAMP * 64 + bid * 2 + tid] = misc[2 + tid] + (DT / 6.0f) * kl;
    }
}

extern "C" void kernel_launch(void* const* d_in, const int* in_sizes, int n_in,
                              void* d_out, int out_size, void* d_ws, size_t ws_size,
                              hipStream_t stream) {
    const float* z  = (const float*)d_in[0];
    const float* W1 = (const float*)d_in[1];
    const float* b1 = (const float*)d_in[2];
    const float* W2 = (const float*)d_in[3];
    const float* b2 = (const float*)d_in[4];
    const float* W3 = (const float*)d_in[5];
    const float* b3 = (const float*)d_in[6];
    const float* W4 = (const float*)d_in[7];
    const float* b4 = (const float*)d_in[8];
    unsigned short* ws = (unsigned short*)d_ws;
    float* out = (float*)d_out;

    hipLaunchKernelGGL(prep_kernel, dim3(256), dim3(256), 0, stream, W1, W2, W3, W4, ws);
    hipLaunchKernelGGL(cnf_kernel, dim3(NSAMP / 2), dim3(512), 0, stream, z, b1, b2, b3, b4, ws, out);
}

// Round 12
// 45288.828 us; speedup vs baseline: 2.9026x; 2.9026x over previous
//
#include <hip/hip_runtime.h>

#define NSAMP 16384
#define NSTEP 32

typedef __attribute__((ext_vector_type(8))) short bf16x8;
typedef __attribute__((ext_vector_type(4))) short short4v;
typedef __attribute__((ext_vector_type(4))) float f32x4;
typedef __attribute__((ext_vector_type(2))) unsigned int uint2v;
typedef __attribute__((ext_vector_type(4))) unsigned int uint4v;

__device__ __forceinline__ unsigned short f2bf(float f) {
    unsigned int u = __float_as_uint(f);
    u += 0x7FFFu + ((u >> 16) & 1u);
    return (unsigned short)(u >> 16);
}
__device__ __forceinline__ float bf2fs(short h) {
    return __uint_as_float(((unsigned int)(unsigned short)h) << 16);
}
__device__ __forceinline__ unsigned int cvtpk(float a, float b) {
    unsigned int r;
    asm("v_cvt_pk_bf16_f32 %0, %1, %2" : "=v"(r) : "v"(a), "v"(b));
    return r;
}
__device__ __forceinline__ float ftanh(float x) {
    float e = __expf(2.0f * x);
    return 1.0f - __fdividef(2.0f, e + 1.0f);
}

// ---------------- prep: pack weights to bf16 in d_ws ----------------
__global__ void prep_kernel(const float* __restrict__ W1, const float* __restrict__ W2,
                            const float* __restrict__ W3, const float* __restrict__ W4,
                            unsigned short* __restrict__ ws) {
    int j = blockIdx.x * blockDim.x + threadIdx.x;   // 0..65535
    if (j < 65536) {
        int e = j & 7, l = (j >> 3) & 63, s = (j >> 9) & 1, ks = (j >> 10) & 7, w = j >> 13;
        int m = (w << 5) + (s << 4) + (l & 15);
        int k = (ks << 5) + ((l >> 4) << 3) + e;
        ws[j]         = f2bf(W2[m * 256 + k]);
        ws[65536 + j] = f2bf(W3[m * 256 + k]);
    }
    if (j < 16384) {
        int i = j >> 8, k = j & 255;
        ws[131072 + j] = f2bf(W1[k * 64 + i]);   // W1T[i][k]
        ws[147456 + j] = f2bf(W4[j]);            // W4[i][k]
        int e = j & 7, l = (j >> 3) & 63, ms = (j >> 9) & 1, ks = (j >> 10) & 1, w = j >> 11;
        int m = (w << 5) + (ms << 4) + (l & 15);
        int i2 = (ks << 5) + ((l >> 4) << 3) + e;
        ws[163840 + j] = f2bf(W1[m * 64 + i2]);  // W1 A-frags (K=64)
    }
}

// ---------------- main persistent-integration kernel ----------------
// R5 structure (best known: 42.9 ms): one block = TWO samples; 8 waves;
// W1/W2/W3 mfma A-fragments register-resident, loaded ONCE pre-loop (any
// in-loop reload triggers compiler remat -> global-load flood; R11 lesson).
// XT rows (stride 264): 0-63 tangent^T s0, 64-127 tangent^T s1,
//   128/129 h1 s0/s1, 130/131 h2 s0/s1.
// R12 micro-edits vs R5: per-lane RK state (no zbv/kav LDS), bf16
// inter-phase vectors (dvec1/d2vec/d3vec/hvec), b4 per-lane.

#define ZERO5()                                                              \
    _Pragma("unroll") for (int ms = 0; ms < 2; ++ms)                         \
    _Pragma("unroll") for (int ns = 0; ns < 5; ++ns)                         \
        acc[ms][ns] = (f32x4){0.f, 0.f, 0.f, 0.f};

#define ZERO4()                                                              \
    _Pragma("unroll") for (int ms = 0; ms < 2; ++ms)                         \
    _Pragma("unroll") for (int ns = 0; ns < 4; ++ns)                         \
        acc[ms][ns] = (f32x4){0.f, 0.f, 0.f, 0.f};

#define GEMM_PASS_A(WF, HBASE)                                               \
    __builtin_amdgcn_s_setprio(1);                                           \
    _Pragma("unroll") for (int ks = 0; ks < 8; ++ks) {                       \
        const int kr = (ks << 5) + kband;                                    \
        bf16x8 bfr[5];                                                       \
        _Pragma("unroll") for (int ns = 0; ns < 4; ++ns)                     \
            bfr[ns] = *(const bf16x8*)&XT[((ns << 4) + lm) * 264 + kr];      \
        bfr[4] = *(const bf16x8*)&XT[(HBASE + (lm & 1)) * 264 + kr];         \
        _Pragma("unroll") for (int ms = 0; ms < 2; ++ms)                     \
        _Pragma("unroll") for (int ns = 0; ns < 5; ++ns)                     \
            acc[ms][ns] = __builtin_amdgcn_mfma_f32_16x16x32_bf16(           \
                WF[ks][ms], bfr[ns], acc[ms][ns], 0, 0, 0);                  \
    }                                                                        \
    __builtin_amdgcn_s_setprio(0);

#define GEMM_PASS_B(WF)                                                      \
    __builtin_amdgcn_s_setprio(1);                                           \
    _Pragma("unroll") for (int ks = 0; ks < 8; ++ks) {                       \
        const int kr = (ks << 5) + kband;                                    \
        bf16x8 bfr[4];                                                       \
        _Pragma("unroll") for (int ns = 0; ns < 4; ++ns)                     \
            bfr[ns] = *(const bf16x8*)&XT[(((ns + 4) << 4) + lm) * 264 + kr];\
        _Pragma("unroll") for (int ms = 0; ms < 2; ++ms)                     \
        _Pragma("unroll") for (int ns = 0; ns < 4; ++ns)                     \
            acc[ms][ns] = __builtin_amdgcn_mfma_f32_16x16x32_bf16(           \
                WF[ks][ms], bfr[ns], acc[ms][ns], 0, 0, 0);                  \
    }                                                                        \
    __builtin_amdgcn_s_setprio(0);

// Wave-sliced tangent build for sample S: wave w writes XT rows S*64+l,
// k-columns [32w, 32w+32). d1 slice (bf16) written by THIS wave in P1.
#define BUILD_SLICE(S)                                                       \
    {                                                                        \
        _Pragma("unroll") for (int c = 0; c < 4; ++c) {                      \
            const int kk = kcol0 + (c << 3);                                 \
            const bf16x8 wv = *(const bf16x8*)&W1T[l * 264 + kk];            \
            const bf16x8 dq = *(const bf16x8*)&dvec1[(S) * 256 + kk];        \
            uint4v o;                                                        \
            o[0] = cvtpk(bf2fs(wv[0]) * bf2fs(dq[0]), bf2fs(wv[1]) * bf2fs(dq[1])); \
            o[1] = cvtpk(bf2fs(wv[2]) * bf2fs(dq[2]), bf2fs(wv[3]) * bf2fs(dq[3])); \
            o[2] = cvtpk(bf2fs(wv[4]) * bf2fs(dq[4]), bf2fs(wv[5]) * bf2fs(dq[5])); \
            o[3] = cvtpk(bf2fs(wv[6]) * bf2fs(dq[6]), bf2fs(wv[7]) * bf2fs(dq[7])); \
            *(uint4v*)&XT[((S) * 64 + l) * 264 + kk] = o;                    \
        }                                                                    \
    }

__launch_bounds__(512, 2)
__global__ void cnf_kernel(const float* __restrict__ zin,
                           const float* __restrict__ b1g, const float* __restrict__ b2g,
                           const float* __restrict__ b3g, const float* __restrict__ b4g,
                           const unsigned short* __restrict__ ws,
                           float* __restrict__ out)
{
    __shared__ __align__(16) unsigned short XT[132 * 264];   // 69.7 KB
    __shared__ __align__(16) unsigned short W1T[64 * 264];   // 33.8 KB
    __shared__ __align__(16) unsigned short W4L[64 * 264];   // 33.8 KB
    __shared__ __align__(16) unsigned short ZBT[16 * 72];    // 2.3 KB
    __shared__ __align__(16) unsigned short dvec1[2 * 256];  // bf16 d1
    __shared__ __align__(16) unsigned short d2vec[2 * 256];  // bf16 d2
    __shared__ __align__(16) unsigned short d3vec[2 * 256];  // bf16 d3
    __shared__ __align__(16) unsigned short hvec[2 * 256];   // bf16 h3
    __shared__ __align__(16) float b1l[256], b2l[256], b3l[256];
    __shared__ float wredp[16];
    __shared__ float misc[4];   // [0..1]=ka_logp per s, [2..3]=logp per s

    const int tid = threadIdx.x;
    const int w = tid >> 6;
    const int l = tid & 63;
    const int lm = l & 15;
    const int bid = blockIdx.x;
    const int r0 = (w << 5) + ((l >> 4) << 2);
    const int kband = (l >> 4) << 3;
    const int kcol0 = w << 5;
    const float DT = -1.0f / 32.0f;

    // per-lane RK state: wave w owns sample sown, lane owns latent dim iown
    const int sown = w >> 2;
    const int iown = ((w & 3) << 4) + lm;
    const float b4r = b4g[iown];
    float zreg = zin[(bid * 2 + sown) * 64 + iown];
    float kreg = 0.f;

    // ---- register-resident weight fragments (loaded ONCE, never reloaded) ----
    bf16x8 w2f[8][2], w3f[8][2], w1f[2][2];
    {
        const bf16x8* w2g = (const bf16x8*)ws;
        const bf16x8* w3g = w2g + 8192;
        const bf16x8* w1g = (const bf16x8*)(ws + 163840);
#pragma unroll
        for (int ks = 0; ks < 8; ++ks)
#pragma unroll
            for (int s = 0; s < 2; ++s) {
                int idx = (((w << 3) + ks) * 2 + s) * 64 + l;
                w2f[ks][s] = w2g[idx];
                w3f[ks][s] = w3g[idx];
            }
#pragma unroll
        for (int ks = 0; ks < 2; ++ks)
#pragma unroll
            for (int ms = 0; ms < 2; ++ms)
                w1f[ks][ms] = w1g[(((w << 1) + ks) * 2 + ms) * 64 + l];
    }
    // ---- LDS init ----
    for (int c = tid; c < 2048; c += 512) {
        int i = c >> 5, k0 = (c & 31) << 3;
        *(bf16x8*)&W1T[i * 264 + k0] = *(const bf16x8*)&ws[131072 + i * 256 + k0];
        *(bf16x8*)&W4L[i * 264 + k0] = *(const bf16x8*)&ws[147456 + i * 256 + k0];
    }
    for (int c = 144 + tid; c < 1152; c += 512) ZBT[c] = 0;   // zero rows 2-15
    for (int c = tid; c < 256; c += 512) { b1l[c] = b1g[c]; b2l[c] = b2g[c]; b3l[c] = b3g[c]; }
    if (tid < 128) {
        const int s = tid >> 6, i = tid & 63;
        ZBT[s * 72 + i] = f2bf(zin[(bid * 2 + s) * 64 + i]);
    }
    if (tid < 2) { misc[tid] = 0.f; misc[2 + tid] = 0.f; }
    __syncthreads();

    for (int it = 0; it < NSTEP * 4; ++it) {
        const int e = it & 3;
        f32x4 acc[2][5];

        // ======== P1: deferred logp + z-MFMA (h1/d1) + tangent build s0 ======
        if (it > 0 && tid < 2) {
            const int ep = (it - 1) & 3;
            float div = 0.f;
#pragma unroll
            for (int q = 0; q < 8; ++q) div += wredp[tid * 8 + q];
            const float wgt = (ep == 0 || ep == 3) ? 1.f : 2.f;
            float kl = (ep == 0) ? -div : misc[tid] - wgt * div;
            misc[tid] = kl;
            if (ep == 3) misc[2 + tid] += (DT / 6.0f) * kl;
        }
        {
            f32x4 az[2];
            az[0] = (f32x4){0.f, 0.f, 0.f, 0.f};
            az[1] = (f32x4){0.f, 0.f, 0.f, 0.f};
#pragma unroll
            for (int ks = 0; ks < 2; ++ks) {
                const bf16x8 zf = *(const bf16x8*)&ZBT[lm * 72 + (ks << 5) + kband];
#pragma unroll
                for (int ms = 0; ms < 2; ++ms)
                    az[ms] = __builtin_amdgcn_mfma_f32_16x16x32_bf16(w1f[ks][ms], zf, az[ms], 0, 0, 0);
            }
#pragma unroll
            for (int ms = 0; ms < 2; ++ms) {
                const int rb = r0 + (ms << 4);
                float hh[4], dd[4];
#pragma unroll
                for (int rg = 0; rg < 4; ++rg) {
                    float h = ftanh(az[ms][rg] + b1l[rb + rg]);
                    hh[rg] = h; dd[rg] = 1.f - h * h;
                }
                if (lm < 2) {
                    uint2v dp; dp[0] = cvtpk(dd[0], dd[1]); dp[1] = cvtpk(dd[2], dd[3]);
                    *(uint2v*)&dvec1[lm * 256 + rb] = dp;
                    uint2v hp; hp[0] = cvtpk(hh[0], hh[1]); hp[1] = cvtpk(hh[2], hh[3]);
                    *(uint2v*)&XT[(128 + lm) * 264 + rb] = hp;
                }
            }
        }
        // wave-local: dvec1 slice [kcol0,kcol0+32) written by THIS wave above
        BUILD_SLICE(0)
        __syncthreads();

        // ======== P2: tangent build s1 + GEMM1 pass A ========
        BUILD_SLICE(1)
        ZERO5();
        GEMM_PASS_A(w2f, 128)
        __syncthreads();

        // ======== P3: epi2A (h2/d2, A2 s0 slice) + GEMM1 pass B ========
        {
#pragma unroll
            for (int ms = 0; ms < 2; ++ms) {
                const int rb = r0 + (ms << 4);
                float hh[4], dd[4];
#pragma unroll
                for (int rg = 0; rg < 4; ++rg) {
                    float h = ftanh(acc[ms][4][rg] + b2l[rb + rg]);
                    hh[rg] = h; dd[rg] = 1.f - h * h;
                }
                if (lm < 2) {
                    uint2v dp; dp[0] = cvtpk(dd[0], dd[1]); dp[1] = cvtpk(dd[2], dd[3]);
                    *(uint2v*)&d2vec[lm * 256 + rb] = dp;
                    uint2v hp; hp[0] = cvtpk(hh[0], hh[1]); hp[1] = cvtpk(hh[2], hh[3]);
                    *(uint2v*)&XT[(130 + lm) * 264 + rb] = hp;
                }
            }
#pragma unroll
            for (int ms = 0; ms < 2; ++ms) {
                const int rb = r0 + (ms << 4);
                const short4v dq = *(const short4v*)&d2vec[rb];        // sample 0 (own rows)
                const float ds0 = bf2fs(dq[0]), ds1 = bf2fs(dq[1]);
                const float ds2 = bf2fs(dq[2]), ds3 = bf2fs(dq[3]);
#pragma unroll
                for (int ns = 0; ns < 4; ++ns) {
                    uint2v o;
                    o[0] = cvtpk(acc[ms][ns][0] * ds0, acc[ms][ns][1] * ds1);
                    o[1] = cvtpk(acc[ms][ns][2] * ds2, acc[ms][ns][3] * ds3);
                    *(uint2v*)&XT[((ns << 4) + lm) * 264 + rb] = o;
                }
            }
            ZERO4();
            GEMM_PASS_B(w2f)
        }
        __syncthreads();

        // ======== P4: epi2B (A2 s1 slice) + GEMM2 pass A ========
        {
#pragma unroll
            for (int ms = 0; ms < 2; ++ms) {
                const int rb = r0 + (ms << 4);
                const short4v dq = *(const short4v*)&d2vec[256 + rb];  // sample 1 (own rows)
                const float ds0 = bf2fs(dq[0]), ds1 = bf2fs(dq[1]);
                const float ds2 = bf2fs(dq[2]), ds3 = bf2fs(dq[3]);
#pragma unroll
                for (int ns = 0; ns < 4; ++ns) {
                    uint2v o;
                    o[0] = cvtpk(acc[ms][ns][0] * ds0, acc[ms][ns][1] * ds1);
                    o[1] = cvtpk(acc[ms][ns][2] * ds2, acc[ms][ns][3] * ds3);
                    *(uint2v*)&XT[(((ns + 4) << 4) + lm) * 264 + rb] = o;
                }
            }
            ZERO5();
            GEMM_PASS_A(w3f, 130)
        }
        __syncthreads();

        // ======== P5: epi3A (h3/d3, div partial s0) + GEMM2 pass B ========
        float p0 = 0.f;
        {
#pragma unroll
            for (int ms = 0; ms < 2; ++ms) {
                const int rb = r0 + (ms << 4);
                float hh[4], dd[4];
#pragma unroll
                for (int rg = 0; rg < 4; ++rg) {
                    float h = ftanh(acc[ms][4][rg] + b3l[rb + rg]);
                    hh[rg] = h; dd[rg] = 1.f - h * h;
                }
                if (lm < 2) {
                    uint2v hp; hp[0] = cvtpk(hh[0], hh[1]); hp[1] = cvtpk(hh[2], hh[3]);
                    *(uint2v*)&hvec[lm * 256 + rb] = hp;
                    uint2v dp; dp[0] = cvtpk(dd[0], dd[1]); dp[1] = cvtpk(dd[2], dd[3]);
                    *(uint2v*)&d3vec[lm * 256 + rb] = dp;
                }
            }
#pragma unroll
            for (int ms = 0; ms < 2; ++ms) {
                const int rb = r0 + (ms << 4);
                const short4v dq = *(const short4v*)&d3vec[rb];        // sample 0 (own rows)
                const float ds0 = bf2fs(dq[0]), ds1 = bf2fs(dq[1]);
                const float ds2 = bf2fs(dq[2]), ds3 = bf2fs(dq[3]);
#pragma unroll
                for (int ns = 0; ns < 4; ++ns) {
                    const short4v wv = *(const short4v*)&W4L[((ns << 4) + lm) * 264 + rb];
                    p0 += acc[ms][ns][0] * ds0 * bf2fs(wv[0]);
                    p0 += acc[ms][ns][1] * ds1 * bf2fs(wv[1]);
                    p0 += acc[ms][ns][2] * ds2 * bf2fs(wv[2]);
                    p0 += acc[ms][ns][3] * ds3 * bf2fs(wv[3]);
                }
            }
            ZERO4();
            GEMM_PASS_B(w3f)
        }
        __syncthreads();

        // ======== P6: epi3B (div s1) + reduces + dz matvec + RK ========
        {
            float p1 = 0.f;
#pragma unroll
            for (int ms = 0; ms < 2; ++ms) {
                const int rb = r0 + (ms << 4);
                const short4v dq = *(const short4v*)&d3vec[256 + rb];  // sample 1 (own rows)
                const float ds0 = bf2fs(dq[0]), ds1 = bf2fs(dq[1]);
                const float ds2 = bf2fs(dq[2]), ds3 = bf2fs(dq[3]);
#pragma unroll
                for (int ns = 0; ns < 4; ++ns) {
                    const short4v wv = *(const short4v*)&W4L[((ns << 4) + lm) * 264 + rb];
                    p1 += acc[ms][ns][0] * ds0 * bf2fs(wv[0]);
                    p1 += acc[ms][ns][1] * ds1 * bf2fs(wv[1]);
                    p1 += acc[ms][ns][2] * ds2 * bf2fs(wv[2]);
                    p1 += acc[ms][ns][3] * ds3 * bf2fs(wv[3]);
                }
            }
#pragma unroll
            for (int o = 32; o; o >>= 1) {
                p0 += __shfl_xor(p0, o, 64);
                p1 += __shfl_xor(p1, o, 64);
            }
            if (l == 0) { wredp[w] = p0; wredp[8 + w] = p1; }

            // dz matvec: wave w owns sample sown, lane dim iown; ch = k-chunk
            const int ch = l >> 4;
            float a = 0.f;
#pragma unroll
            for (int c = 0; c < 8; ++c) {
                const bf16x8 wv = *(const bf16x8*)&W4L[iown * 264 + (ch << 6) + (c << 3)];
                const bf16x8 hb = *(const bf16x8*)&hvec[sown * 256 + (ch << 6) + (c << 3)];
                a += bf2fs(wv[0]) * bf2fs(hb[0]) + bf2fs(wv[1]) * bf2fs(hb[1]);
                a += bf2fs(wv[2]) * bf2fs(hb[2]) + bf2fs(wv[3]) * bf2fs(hb[3]);
                a += bf2fs(wv[4]) * bf2fs(hb[4]) + bf2fs(wv[5]) * bf2fs(hb[5]);
                a += bf2fs(wv[6]) * bf2fs(hb[6]) + bf2fs(wv[7]) * bf2fs(hb[7]);
            }
            a += __shfl_xor(a, 16, 64);
            a += __shfl_xor(a, 32, 64);
            const float dz = a + b4r;

            const float wgt = (e == 0 || e == 3) ? 1.f : 2.f;
            const float kv = (e == 0) ? dz : kreg + wgt * dz;
            kreg = kv;
            float znew;
            if (e < 3) {
                znew = zreg + ((e == 2) ? 1.0f : 0.5f) * DT * dz;
            } else {
                znew = zreg + (DT / 6.0f) * kv;
                zreg = znew;
            }
            if (l < 16) ZBT[sown * 72 + iown] = f2bf(znew);
        }
        __syncthreads();
    }

    // final outputs
    if (l < 16) out[(bid * 2 + sown) * 64 + iown] = zreg;
    if (tid < 2) {
        float div = 0.f;
#pragma unroll
        for (int q = 0; q < 8; ++q) div += wredp[tid * 8 + q];
        float kl = misc[tid] - div;
        out[NSAMP * 64 + bid * 2 + tid] = misc[2 + tid] + (DT / 6.0f) * kl;
    }
}

extern "C" void kernel_launch(void* const* d_in, const int* in_sizes, int n_in,
                              void* d_out, int out_size, void* d_ws, size_t ws_size,
                              hipStream_t stream) {
    const float* z  = (const float*)d_in[0];
    const float* W1 = (const float*)d_in[1];
    const float* b1 = (const float*)d_in[2];
    const float* W2 = (const float*)d_in[3];
    const float* b2 = (const float*)d_in[4];
    const float* W3 = (const float*)d_in[5];
    const float* b3 = (const float*)d_in[6];
    const float* W4 = (const float*)d_in[7];
    const float* b4 = (const float*)d_in[8];
    unsigned short* ws = (unsigned short*)d_ws;
    float* out = (float*)d_out;

    hipLaunchKernelGGL(prep_kernel, dim3(256), dim3(256), 0, stream, W1, W2, W3, W4, ws);
    hipLaunchKernelGGL(cnf_kernel, dim3(NSAMP / 2), dim3(512), 0, stream, z, b1, b2, b3, b4, ws, out);
}

// Round 13
// 42526.279 us; speedup vs baseline: 3.0911x; 1.0650x over previous
//
#include <hip/hip_runtime.h>

#define NSAMP 16384
#define NSTEP 32

typedef __attribute__((ext_vector_type(8))) short bf16x8;
typedef __attribute__((ext_vector_type(4))) short short4v;
typedef __attribute__((ext_vector_type(4))) float f32x4;
typedef __attribute__((ext_vector_type(2))) unsigned int uint2v;
typedef __attribute__((ext_vector_type(4))) unsigned int uint4v;

__device__ __forceinline__ unsigned short f2bf(float f) {
    unsigned int u = __float_as_uint(f);
    u += 0x7FFFu + ((u >> 16) & 1u);
    return (unsigned short)(u >> 16);
}
__device__ __forceinline__ float bf2fs(short h) {
    return __uint_as_float(((unsigned int)(unsigned short)h) << 16);
}
__device__ __forceinline__ unsigned int cvtpk(float a, float b) {
    unsigned int r;
    asm("v_cvt_pk_bf16_f32 %0, %1, %2" : "=v"(r) : "v"(a), "v"(b));
    return r;
}
__device__ __forceinline__ float ftanh(float x) {
    float e = __expf(2.0f * x);
    return 1.0f - __fdividef(2.0f, e + 1.0f);
}

// ---------------- prep: pack weights to bf16 in d_ws ----------------
__global__ void prep_kernel(const float* __restrict__ W1, const float* __restrict__ W2,
                            const float* __restrict__ W3, const float* __restrict__ W4,
                            unsigned short* __restrict__ ws) {
    int j = blockIdx.x * blockDim.x + threadIdx.x;   // 0..65535
    if (j < 65536) {
        int e = j & 7, l = (j >> 3) & 63, s = (j >> 9) & 1, ks = (j >> 10) & 7, w = j >> 13;
        int m = (w << 5) + (s << 4) + (l & 15);
        int k = (ks << 5) + ((l >> 4) << 3) + e;
        ws[j]         = f2bf(W2[m * 256 + k]);
        ws[65536 + j] = f2bf(W3[m * 256 + k]);
    }
    if (j < 16384) {
        int i = j >> 8, k = j & 255;
        ws[131072 + j] = f2bf(W1[k * 64 + i]);   // W1T[i][k]
        ws[147456 + j] = f2bf(W4[j]);            // W4[i][k]
        int e = j & 7, l = (j >> 3) & 63, ms = (j >> 9) & 1, ks = (j >> 10) & 1, w = j >> 11;
        int m = (w << 5) + (ms << 4) + (l & 15);
        int i2 = (ks << 5) + ((l >> 4) << 3) + e;
        ws[163840 + j] = f2bf(W1[m * 64 + i2]);  // W1 A-frags (K=64)
    }
}

// ---------------- main persistent-integration kernel ----------------
// R5 structure (best known: 42.9 ms) + per-lane RK state only (R12's safe
// half). One block = TWO samples; 8 waves; W1/W2/W3 mfma A-fragments
// register-resident, loaded ONCE pre-loop (in-loop reload => remat flood).
// XT rows (stride 264): 0-63 tangent^T s0, 64-127 tangent^T s1,
//   128/129 h1 s0/s1, 130/131 h2 s0/s1.

#define ZERO5()                                                              \
    _Pragma("unroll") for (int ms = 0; ms < 2; ++ms)                         \
    _Pragma("unroll") for (int ns = 0; ns < 5; ++ns)                         \
        acc[ms][ns] = (f32x4){0.f, 0.f, 0.f, 0.f};

#define ZERO4()                                                              \
    _Pragma("unroll") for (int ms = 0; ms < 2; ++ms)                         \
    _Pragma("unroll") for (int ns = 0; ns < 4; ++ns)                         \
        acc[ms][ns] = (f32x4){0.f, 0.f, 0.f, 0.f};

#define GEMM_PASS_A(WF, HBASE)                                               \
    __builtin_amdgcn_s_setprio(1);                                           \
    _Pragma("unroll") for (int ks = 0; ks < 8; ++ks) {                       \
        const int kr = (ks << 5) + kband;                                    \
        bf16x8 bfr[5];                                                       \
        _Pragma("unroll") for (int ns = 0; ns < 4; ++ns)                     \
            bfr[ns] = *(const bf16x8*)&XT[((ns << 4) + lm) * 264 + kr];      \
        bfr[4] = *(const bf16x8*)&XT[(HBASE + (lm & 1)) * 264 + kr];         \
        _Pragma("unroll") for (int ms = 0; ms < 2; ++ms)                     \
        _Pragma("unroll") for (int ns = 0; ns < 5; ++ns)                     \
            acc[ms][ns] = __builtin_amdgcn_mfma_f32_16x16x32_bf16(           \
                WF[ks][ms], bfr[ns], acc[ms][ns], 0, 0, 0);                  \
    }                                                                        \
    __builtin_amdgcn_s_setprio(0);

#define GEMM_PASS_B(WF)                                                      \
    __builtin_amdgcn_s_setprio(1);                                           \
    _Pragma("unroll") for (int ks = 0; ks < 8; ++ks) {                       \
        const int kr = (ks << 5) + kband;                                    \
        bf16x8 bfr[4];                                                       \
        _Pragma("unroll") for (int ns = 0; ns < 4; ++ns)                     \
            bfr[ns] = *(const bf16x8*)&XT[(((ns + 4) << 4) + lm) * 264 + kr];\
        _Pragma("unroll") for (int ms = 0; ms < 2; ++ms)                     \
        _Pragma("unroll") for (int ns = 0; ns < 4; ++ns)                     \
            acc[ms][ns] = __builtin_amdgcn_mfma_f32_16x16x32_bf16(           \
                WF[ks][ms], bfr[ns], acc[ms][ns], 0, 0, 0);                  \
    }                                                                        \
    __builtin_amdgcn_s_setprio(0);

// Wave-sliced tangent build for sample S: wave w writes XT rows S*64+l,
// k-columns [32w, 32w+32). d1 slice (f32) written by THIS wave in P1.
#define BUILD_SLICE(S)                                                       \
    {                                                                        \
        _Pragma("unroll") for (int c = 0; c < 4; ++c) {                      \
            const int kk = kcol0 + (c << 3);                                 \
            const bf16x8 wv = *(const bf16x8*)&W1T[l * 264 + kk];            \
            const float4 d0 = *(const float4*)&dvec1[(S)*256 + kk];          \
            const float4 d1_ = *(const float4*)&dvec1[(S)*256 + kk + 4];     \
            uint4v o;                                                        \
            o[0] = cvtpk(bf2fs(wv[0]) * d0.x, bf2fs(wv[1]) * d0.y);          \
            o[1] = cvtpk(bf2fs(wv[2]) * d0.z, bf2fs(wv[3]) * d0.w);          \
            o[2] = cvtpk(bf2fs(wv[4]) * d1_.x, bf2fs(wv[5]) * d1_.y);        \
            o[3] = cvtpk(bf2fs(wv[6]) * d1_.z, bf2fs(wv[7]) * d1_.w);        \
            *(uint4v*)&XT[((S)*64 + l) * 264 + kk] = o;                      \
        }                                                                    \
    }

__launch_bounds__(512, 2)
__global__ void cnf_kernel(const float* __restrict__ zin,
                           const float* __restrict__ b1g, const float* __restrict__ b2g,
                           const float* __restrict__ b3g, const float* __restrict__ b4g,
                           const unsigned short* __restrict__ ws,
                           float* __restrict__ out)
{
    __shared__ __align__(16) unsigned short XT[132 * 264];   // 69.7 KB
    __shared__ __align__(16) unsigned short W1T[64 * 264];   // 33.8 KB
    __shared__ __align__(16) unsigned short W4L[64 * 264];   // 33.8 KB
    __shared__ __align__(16) unsigned short ZBT[16 * 72];    // 2.3 KB
    __shared__ __align__(16) float dvec1[2 * 256];
    __shared__ __align__(16) float d2vec[2 * 256];
    __shared__ __align__(16) float d3vec[2 * 256];
    __shared__ __align__(16) float hvec[2 * 256];
    __shared__ __align__(16) float b1l[256], b2l[256], b3l[256];
    __shared__ float wredp[16];
    __shared__ float misc[4];   // [0..1]=ka_logp per s, [2..3]=logp per s

    const int tid = threadIdx.x;
    const int w = tid >> 6;
    const int l = tid & 63;
    const int lm = l & 15;
    const int bid = blockIdx.x;
    const int r0 = (w << 5) + ((l >> 4) << 2);
    const int kband = (l >> 4) << 3;
    const int kcol0 = w << 5;
    const float DT = -1.0f / 32.0f;

    // per-lane RK state: wave w owns sample sown, lane owns latent dim iown
    const int sown = w >> 2;
    const int iown = ((w & 3) << 4) + lm;
    const float b4r = b4g[iown];
    float zreg = zin[(bid * 2 + sown) * 64 + iown];
    float kreg = 0.f;

    // ---- register-resident weight fragments (loaded ONCE, never reloaded) ----
    bf16x8 w2f[8][2], w3f[8][2], w1f[2][2];
    {
        const bf16x8* w2g = (const bf16x8*)ws;
        const bf16x8* w3g = w2g + 8192;
        const bf16x8* w1g = (const bf16x8*)(ws + 163840);
#pragma unroll
        for (int ks = 0; ks < 8; ++ks)
#pragma unroll
            for (int s = 0; s < 2; ++s) {
                int idx = (((w << 3) + ks) * 2 + s) * 64 + l;
                w2f[ks][s] = w2g[idx];
                w3f[ks][s] = w3g[idx];
            }
#pragma unroll
        for (int ks = 0; ks < 2; ++ks)
#pragma unroll
            for (int ms = 0; ms < 2; ++ms)
                w1f[ks][ms] = w1g[(((w << 1) + ks) * 2 + ms) * 64 + l];
    }
    // ---- LDS init ----
    for (int c = tid; c < 2048; c += 512) {
        int i = c >> 5, k0 = (c & 31) << 3;
        *(bf16x8*)&W1T[i * 264 + k0] = *(const bf16x8*)&ws[131072 + i * 256 + k0];
        *(bf16x8*)&W4L[i * 264 + k0] = *(const bf16x8*)&ws[147456 + i * 256 + k0];
    }
    for (int c = 144 + tid; c < 1152; c += 512) ZBT[c] = 0;   // zero rows 2-15
    for (int c = tid; c < 256; c += 512) { b1l[c] = b1g[c]; b2l[c] = b2g[c]; b3l[c] = b3g[c]; }
    if (tid < 128) {
        const int s = tid >> 6, i = tid & 63;
        ZBT[s * 72 + i] = f2bf(zin[(bid * 2 + s) * 64 + i]);
    }
    if (tid < 2) { misc[tid] = 0.f; misc[2 + tid] = 0.f; }
    __syncthreads();

    for (int it = 0; it < NSTEP * 4; ++it) {
        const int e = it & 3;
        f32x4 acc[2][5];

        // ======== P1: deferred logp + z-MFMA (h1/d1) + tangent build s0 ======
        if (it > 0 && tid < 2) {
            const int ep = (it - 1) & 3;
            float div = 0.f;
#pragma unroll
            for (int q = 0; q < 8; ++q) div += wredp[tid * 8 + q];
            const float wgt = (ep == 0 || ep == 3) ? 1.f : 2.f;
            float kl = (ep == 0) ? -div : misc[tid] - wgt * div;
            misc[tid] = kl;
            if (ep == 3) misc[2 + tid] += (DT / 6.0f) * kl;
        }
        {
            f32x4 az[2];
            az[0] = (f32x4){0.f, 0.f, 0.f, 0.f};
            az[1] = (f32x4){0.f, 0.f, 0.f, 0.f};
#pragma unroll
            for (int ks = 0; ks < 2; ++ks) {
                const bf16x8 zf = *(const bf16x8*)&ZBT[lm * 72 + (ks << 5) + kband];
#pragma unroll
                for (int ms = 0; ms < 2; ++ms)
                    az[ms] = __builtin_amdgcn_mfma_f32_16x16x32_bf16(w1f[ks][ms], zf, az[ms], 0, 0, 0);
            }
#pragma unroll
            for (int ms = 0; ms < 2; ++ms) {
                const int rb = r0 + (ms << 4);
                float hh[4], dd[4];
#pragma unroll
                for (int rg = 0; rg < 4; ++rg) {
                    float h = ftanh(az[ms][rg] + b1l[rb + rg]);
                    hh[rg] = h; dd[rg] = 1.f - h * h;
                }
                if (lm < 2) {
                    *(float4*)&dvec1[lm * 256 + rb] = make_float4(dd[0], dd[1], dd[2], dd[3]);
                    uint2v hp; hp[0] = cvtpk(hh[0], hh[1]); hp[1] = cvtpk(hh[2], hh[3]);
                    *(uint2v*)&XT[(128 + lm) * 264 + rb] = hp;
                }
            }
        }
        // wave-local: dvec1 slice [kcol0,kcol0+32) written by THIS wave above
        BUILD_SLICE(0)
        __syncthreads();

        // ======== P2: tangent build s1 + GEMM1 pass A ========
        BUILD_SLICE(1)
        ZERO5();
        GEMM_PASS_A(w2f, 128)
        __syncthreads();

        // ======== P3: epi2A (h2/d2, A2 s0 slice) + GEMM1 pass B ========
        {
#pragma unroll
            for (int ms = 0; ms < 2; ++ms) {
                const int rb = r0 + (ms << 4);
                float hh[4], dd[4];
#pragma unroll
                for (int rg = 0; rg < 4; ++rg) {
                    float h = ftanh(acc[ms][4][rg] + b2l[rb + rg]);
                    hh[rg] = h; dd[rg] = 1.f - h * h;
                }
                if (lm < 2) {
                    *(float4*)&d2vec[lm * 256 + rb] = make_float4(dd[0], dd[1], dd[2], dd[3]);
                    uint2v hp; hp[0] = cvtpk(hh[0], hh[1]); hp[1] = cvtpk(hh[2], hh[3]);
                    *(uint2v*)&XT[(130 + lm) * 264 + rb] = hp;
                }
            }
#pragma unroll
            for (int ms = 0; ms < 2; ++ms) {
                const int rb = r0 + (ms << 4);
                const float4 ds = *(const float4*)&d2vec[rb];          // sample 0 (own rows)
#pragma unroll
                for (int ns = 0; ns < 4; ++ns) {
                    uint2v o;
                    o[0] = cvtpk(acc[ms][ns][0] * ds.x, acc[ms][ns][1] * ds.y);
                    o[1] = cvtpk(acc[ms][ns][2] * ds.z, acc[ms][ns][3] * ds.w);
                    *(uint2v*)&XT[((ns << 4) + lm) * 264 + rb] = o;
                }
            }
            ZERO4();
            GEMM_PASS_B(w2f)
        }
        __syncthreads();

        // ======== P4: epi2B (A2 s1 slice) + GEMM2 pass A ========
        {
#pragma unroll
            for (int ms = 0; ms < 2; ++ms) {
                const int rb = r0 + (ms << 4);
                const float4 ds = *(const float4*)&d2vec[256 + rb];    // sample 1 (own rows)
#pragma unroll
                for (int ns = 0; ns < 4; ++ns) {
                    uint2v o;
                    o[0] = cvtpk(acc[ms][ns][0] * ds.x, acc[ms][ns][1] * ds.y);
                    o[1] = cvtpk(acc[ms][ns][2] * ds.z, acc[ms][ns][3] * ds.w);
                    *(uint2v*)&XT[(((ns + 4) << 4) + lm) * 264 + rb] = o;
                }
            }
            ZERO5();
            GEMM_PASS_A(w3f, 130)
        }
        __syncthreads();

        // ======== P5: epi3A (h3/d3, div partial s0) + GEMM2 pass B ========
        float p0 = 0.f;
        {
#pragma unroll
            for (int ms = 0; ms < 2; ++ms) {
                const int rb = r0 + (ms << 4);
                float hh[4], dd[4];
#pragma unroll
                for (int rg = 0; rg < 4; ++rg) {
                    float h = ftanh(acc[ms][4][rg] + b3l[rb + rg]);
                    hh[rg] = h; dd[rg] = 1.f - h * h;
                }
                if (lm < 2) {
                    *(float4*)&hvec[lm * 256 + rb] = make_float4(hh[0], hh[1], hh[2], hh[3]);
                    *(float4*)&d3vec[lm * 256 + rb] = make_float4(dd[0], dd[1], dd[2], dd[3]);
                }
            }
#pragma unroll
            for (int ms = 0; ms < 2; ++ms) {
                const int rb = r0 + (ms << 4);
                const float4 ds = *(const float4*)&d3vec[rb];          // sample 0 (own rows)
#pragma unroll
                for (int ns = 0; ns < 4; ++ns) {
                    const short4v wv = *(const short4v*)&W4L[((ns << 4) + lm) * 264 + rb];
                    p0 += acc[ms][ns][0] * ds.x * bf2fs(wv[0]);
                    p0 += acc[ms][ns][1] * ds.y * bf2fs(wv[1]);
                    p0 += acc[ms][ns][2] * ds.z * bf2fs(wv[2]);
                    p0 += acc[ms][ns][3] * ds.w * bf2fs(wv[3]);
                }
            }
            ZERO4();
            GEMM_PASS_B(w3f)
        }
        __syncthreads();

        // ======== P6: epi3B (div s1) + reduces + dz matvec + RK ========
        {
            float p1 = 0.f;
#pragma unroll
            for (int ms = 0; ms < 2; ++ms) {
                const int rb = r0 + (ms << 4);
                const float4 ds = *(const float4*)&d3vec[256 + rb];    // sample 1 (own rows)
#pragma unroll
                for (int ns = 0; ns < 4; ++ns) {
                    const short4v wv = *(const short4v*)&W4L[((ns << 4) + lm) * 264 + rb];
                    p1 += acc[ms][ns][0] * ds.x * bf2fs(wv[0]);
                    p1 += acc[ms][ns][1] * ds.y * bf2fs(wv[1]);
                    p1 += acc[ms][ns][2] * ds.z * bf2fs(wv[2]);
                    p1 += acc[ms][ns][3] * ds.w * bf2fs(wv[3]);
                }
            }
#pragma unroll
            for (int o = 32; o; o >>= 1) {
                p0 += __shfl_xor(p0, o, 64);
                p1 += __shfl_xor(p1, o, 64);
            }
            if (l == 0) { wredp[w] = p0; wredp[8 + w] = p1; }

            // dz matvec: wave w owns sample sown, lane dim iown; ch = k-chunk
            const int ch = l >> 4;
            const unsigned short* wr = &W4L[iown * 264 + (ch << 6)];
            const float* hv = &hvec[sown * 256 + (ch << 6)];
            float a = 0.f;
#pragma unroll
            for (int c = 0; c < 8; ++c) {
                bf16x8 wv = *(const bf16x8*)&wr[c * 8];
                float4 h0 = *(const float4*)&hv[c * 8];
                float4 h1 = *(const float4*)&hv[c * 8 + 4];
                a += bf2fs(wv[0]) * h0.x + bf2fs(wv[1]) * h0.y + bf2fs(wv[2]) * h0.z + bf2fs(wv[3]) * h0.w;
                a += bf2fs(wv[4]) * h1.x + bf2fs(wv[5]) * h1.y + bf2fs(wv[6]) * h1.z + bf2fs(wv[7]) * h1.w;
            }
            a += __shfl_xor(a, 16, 64);
            a += __shfl_xor(a, 32, 64);
            const float dz = a + b4r;

            const float wgt = (e == 0 || e == 3) ? 1.f : 2.f;
            const float kv = (e == 0) ? dz : kreg + wgt * dz;
            kreg = kv;
            float znew;
            if (e < 3) {
                znew = zreg + ((e == 2) ? 1.0f : 0.5f) * DT * dz;
            } else {
                znew = zreg + (DT / 6.0f) * kv;
                zreg = znew;
            }
            if (l < 16) ZBT[sown * 72 + iown] = f2bf(znew);
        }
        __syncthreads();
    }

    // final outputs
    if (l < 16) out[(bid * 2 + sown) * 64 + iown] = zreg;
    if (tid < 2) {
        float div = 0.f;
#pragma unroll
        for (int q = 0; q < 8; ++q) div += wredp[tid * 8 + q];
        float kl = misc[tid] - div;
        out[NSAMP * 64 + bid * 2 + tid] = misc[2 + tid] + (DT / 6.0f) * kl;
    }
}

extern "C" void kernel_launch(void* const* d_in, const int* in_sizes, int n_in,
                              void* d_out, int out_size, void* d_ws, size_t ws_size,
                              hipStream_t stream) {
    const float* z  = (const float*)d_in[0];
    const float* W1 = (const float*)d_in[1];
    const float* b1 = (const float*)d_in[2];
    const float* W2 = (const float*)d_in[3];
    const float* b2 = (const float*)d_in[4];
    const float* W3 = (const float*)d_in[5];
    const float* b3 = (const float*)d_in[6];
    const float* W4 = (const float*)d_in[7];
    const float* b4 = (const float*)d_in[8];
    unsigned short* ws = (unsigned short*)d_ws;
    float* out = (float*)d_out;

    hipLaunchKernelGGL(prep_kernel, dim3(256), dim3(256), 0, stream, W1, W2, W3, W4, ws);
    hipLaunchKernelGGL(cnf_kernel, dim3(NSAMP / 2), dim3(512), 0, stream, z, b1, b2, b3, b4, ws, out);
}